// Round 3
// baseline (744.244 us; speedup 1.0000x reference)
//
#include <hip/hip_runtime.h>

// TemporalAttention N=8192 D=1024 — pure fp32 problem (inputs AND output fp32;
// threshold arithmetic shows no bf16 floor). Internals fp16-MFMA.
// Pipeline: cvt fp32->fp16 (x, Wq, Wk, Wv) | QKV gemm_bt | S=QK^T + decay bias
// (fp16 S + per-tile (m,l)) | combine stats | P=exp(S-M)/L in place | O=PV fp32.

using half8   = __attribute__((ext_vector_type(8))) _Float16;
using half4   = __attribute__((ext_vector_type(4))) _Float16;
using floatx4 = __attribute__((ext_vector_type(4))) float;

__device__ __forceinline__ void gload_lds16(const void* g, void* l) {
  __builtin_amdgcn_global_load_lds((const __attribute__((address_space(1))) void*)g,
                                   (__attribute__((address_space(3))) void*)l,
                                   16, 0, 0);
}

// C = A(MxK) * B(NxK)^T, A/B row-major fp16, fp32 accum. 128x128 tile, BK=32,
// 4 waves of 4x4 16x16x32 MFMA.
// BIAS_MODE: 0 none, 1 per-col, 2 per-row. OUT_MODE: 0 fp16, 2 fp32.
template<int BIAS_MODE, int OUT_MODE>
__global__ __launch_bounds__(256)
void gemm_bt_k(const _Float16* __restrict__ A, const _Float16* __restrict__ B,
               void* __restrict__ Cout, const float* __restrict__ bias,
               int Nld, int K, float outScale)
{
  __shared__ __align__(16) _Float16 As[128 * 32];
  __shared__ __align__(16) _Float16 Bs[128 * 32];
  const int tid = threadIdx.x;
  const int w = tid >> 6, lane = tid & 63;
  const int q = lane >> 4, l15 = lane & 15;
  const int wr = w >> 1, wc = w & 1;
  const long rowBase = (long)blockIdx.y * 128;
  const long colBase = (long)blockIdx.x * 128;

  // staging: tile elem e = w*1024 + s*512 + lane*8 -> row e/32, col e%32
  const int e0 = w * 1024 + lane * 8;
  const int r0 = e0 >> 5, c0 = e0 & 31;
  const int r1 = (e0 + 512) >> 5, c1 = (e0 + 512) & 31;
  const _Float16* Ag0 = A + (rowBase + r0) * K + c0;
  const _Float16* Ag1 = A + (rowBase + r1) * K + c1;
  const _Float16* Bg0 = B + (colBase + r0) * K + c0;
  const _Float16* Bg1 = B + (colBase + r1) * K + c1;
  _Float16* Al0 = &As[w * 1024];
  _Float16* Al1 = &As[w * 1024 + 512];
  _Float16* Bl0 = &Bs[w * 1024];
  _Float16* Bl1 = &Bs[w * 1024 + 512];

  floatx4 acc[4][4] = {};

  for (int k0 = 0; k0 < K; k0 += 32) {
    __syncthreads();
    gload_lds16(Ag0, Al0);
    gload_lds16(Ag1, Al1);
    gload_lds16(Bg0, Bl0);
    gload_lds16(Bg1, Bl1);
    Ag0 += 32; Ag1 += 32; Bg0 += 32; Bg1 += 32;
    __syncthreads();
    half8 a[4], b[4];
#pragma unroll
    for (int i = 0; i < 4; ++i)
      a[i] = *(const half8*)&As[(wr * 64 + 16 * i + l15) * 32 + q * 8];
#pragma unroll
    for (int j = 0; j < 4; ++j)
      b[j] = *(const half8*)&Bs[(wc * 64 + 16 * j + l15) * 32 + q * 8];
#pragma unroll
    for (int i = 0; i < 4; ++i)
#pragma unroll
      for (int j = 0; j < 4; ++j)
        acc[i][j] = __builtin_amdgcn_mfma_f32_16x16x32_f16(a[i], b[j], acc[i][j], 0, 0, 0);
  }

#pragma unroll
  for (int i = 0; i < 4; ++i) {
#pragma unroll
    for (int r = 0; r < 4; ++r) {
      const long rowg = rowBase + wr * 64 + 16 * i + q * 4 + r;
#pragma unroll
      for (int j = 0; j < 4; ++j) {
        const long colg = colBase + wc * 64 + 16 * j + l15;
        float v = acc[i][j][r];
        if (BIAS_MODE == 1) v += bias[colg];
        if (BIAS_MODE == 2) v += bias[rowg];
        v *= outScale;
        if (OUT_MODE == 2) ((float*)Cout)[rowg * Nld + colg] = v;
        else               ((_Float16*)Cout)[rowg * Nld + colg] = (_Float16)v;
      }
    }
  }
}

// S = Q*K^T + decay bias; store S fp16; emit per-(row, col-tile) partial (m, l).
__global__ __launch_bounds__(256)
void gemm_stats_k(const _Float16* __restrict__ A, const _Float16* __restrict__ B,
                  const float* __restrict__ ts, _Float16* __restrict__ S,
                  float2* __restrict__ part, int N, int K)
{
  __shared__ __align__(16) _Float16 As[128 * 32];
  __shared__ __align__(16) _Float16 Bs[128 * 32];
  __shared__ float trs[128], tcs[128];
  __shared__ float sM[2][2][64];
  __shared__ float sL[2][2][64];
  const int tid = threadIdx.x;
  const int w = tid >> 6, lane = tid & 63;
  const int q = lane >> 4, l15 = lane & 15;
  const int wr = w >> 1, wc = w & 1;
  const long rowBase = (long)blockIdx.y * 128;
  const long colBase = (long)blockIdx.x * 128;

  if (tid < 128) {
    trs[tid] = ts[rowBase + tid];
    tcs[tid] = ts[colBase + tid];
  }

  const int e0 = w * 1024 + lane * 8;
  const int r0 = e0 >> 5, c0 = e0 & 31;
  const int r1 = (e0 + 512) >> 5, c1 = (e0 + 512) & 31;
  const _Float16* Ag0 = A + (rowBase + r0) * K + c0;
  const _Float16* Ag1 = A + (rowBase + r1) * K + c1;
  const _Float16* Bg0 = B + (colBase + r0) * K + c0;
  const _Float16* Bg1 = B + (colBase + r1) * K + c1;
  _Float16* Al0 = &As[w * 1024];
  _Float16* Al1 = &As[w * 1024 + 512];
  _Float16* Bl0 = &Bs[w * 1024];
  _Float16* Bl1 = &Bs[w * 1024 + 512];

  floatx4 acc[4][4] = {};

  for (int k0 = 0; k0 < K; k0 += 32) {
    __syncthreads();
    gload_lds16(Ag0, Al0);
    gload_lds16(Ag1, Al1);
    gload_lds16(Bg0, Bl0);
    gload_lds16(Bg1, Bl1);
    Ag0 += 32; Ag1 += 32; Bg0 += 32; Bg1 += 32;
    __syncthreads();
    half8 a[4], b[4];
#pragma unroll
    for (int i = 0; i < 4; ++i)
      a[i] = *(const half8*)&As[(wr * 64 + 16 * i + l15) * 32 + q * 8];
#pragma unroll
    for (int j = 0; j < 4; ++j)
      b[j] = *(const half8*)&Bs[(wc * 64 + 16 * j + l15) * 32 + q * 8];
#pragma unroll
    for (int i = 0; i < 4; ++i)
#pragma unroll
      for (int j = 0; j < 4; ++j)
        acc[i][j] = __builtin_amdgcn_mfma_f32_16x16x32_f16(a[i], b[j], acc[i][j], 0, 0, 0);
  }

  const float inv_td = 1.0f / 86400.0f;
  // bias + store S (log(exp(-a)+1e-10) ~= -a to 2.2e-6 since a <= 10)
#pragma unroll
  for (int i = 0; i < 4; ++i) {
#pragma unroll
    for (int r = 0; r < 4; ++r) {
      const int rowl = wr * 64 + 16 * i + q * 4 + r;
#pragma unroll
      for (int j = 0; j < 4; ++j) {
        const int coll = wc * 64 + 16 * j + l15;
        float sv = acc[i][j][r] - fabsf(trs[rowl] - tcs[coll]) * inv_td;
        acc[i][j][r] = sv;
        S[(rowBase + rowl) * (long)N + (colBase + coll)] = (_Float16)sv;
      }
    }
  }
  // per-row (m, l) within this 128-col tile; 16 lanes of a quad share a row
#pragma unroll
  for (int i = 0; i < 4; ++i) {
#pragma unroll
    for (int r = 0; r < 4; ++r) {
      float mx = acc[i][0][r];
#pragma unroll
      for (int j = 1; j < 4; ++j) mx = fmaxf(mx, acc[i][j][r]);
      for (int mask = 1; mask <= 8; mask <<= 1)
        mx = fmaxf(mx, __shfl_xor(mx, mask, 64));
      float ls = 0.0f;
#pragma unroll
      for (int j = 0; j < 4; ++j) ls += __expf(acc[i][j][r] - mx);
      for (int mask = 1; mask <= 8; mask <<= 1)
        ls += __shfl_xor(ls, mask, 64);
      if (l15 == 0) {
        sM[wr][wc][16 * i + 4 * q + r] = mx;
        sL[wr][wc][16 * i + 4 * q + r] = ls;
      }
    }
  }
  __syncthreads();
  if (tid < 128) {
    const int wr2 = tid >> 6, rl = tid & 63;
    const float M0 = sM[wr2][0][rl], M1 = sM[wr2][1][rl];
    const float L0 = sL[wr2][0][rl], L1 = sL[wr2][1][rl];
    const float Mx = fmaxf(M0, M1);
    const float L = L0 * __expf(M0 - Mx) + L1 * __expf(M1 - Mx);
    part[(rowBase + tid) * 64 + blockIdx.x] = make_float2(Mx, L);
  }
}

__global__ void combine_k(const float2* __restrict__ part, float2* __restrict__ fin) {
  const int r = blockIdx.x * 256 + threadIdx.x;
  float M = -3.0e38f;
  for (int c = 0; c < 64; ++c) M = fmaxf(M, part[(long)r * 64 + c].x);
  float L = 0.0f;
  for (int c = 0; c < 64; ++c) {
    const float2 p = part[(long)r * 64 + c];
    L += p.y * __expf(p.x - M);
  }
  fin[r] = make_float2(M, 1.0f / L);
}

// In-place S -> P = exp(s - M) / L (fp16), 8 elems/thread, row = i/8192
__global__ void make_p_k(_Float16* __restrict__ S, const float2* __restrict__ fin) {
  const long i = ((long)blockIdx.x * 256 + threadIdx.x) * 8;
  const int row = (int)(i >> 13);
  const float2 st = fin[row];
  half8 h = *(const half8*)(S + i);
  half8 o;
#pragma unroll
  for (int k = 0; k < 8; ++k)
    o[k] = (_Float16)(__expf((float)h[k] - st.x) * st.y);
  *(half8*)(S + i) = o;
}

// fp32 -> fp16, 4/thread
__global__ void cvt_k(const float* __restrict__ in, _Float16* __restrict__ out, int n) {
  const int i = (blockIdx.x * 256 + threadIdx.x) * 4;
  if (i >= n) return;
  const float4 v = *(const float4*)(in + i);
  half4 o = { (_Float16)v.x, (_Float16)v.y, (_Float16)v.z, (_Float16)v.w };
  *(half4*)(out + i) = o;
}

extern "C" void kernel_launch(void* const* d_in, const int* in_sizes, int n_in,
                              void* d_out, int out_size, void* d_ws, size_t ws_size,
                              hipStream_t stream)
{
  (void)in_sizes; (void)n_in; (void)out_size; (void)ws_size;
  const int N = 8192, D = 1024;
  const float* x  = (const float*)d_in[0];
  const float* ts = (const float*)d_in[1];
  const float* Wq = (const float*)d_in[2];
  const float* bq = (const float*)d_in[3];
  const float* Wk = (const float*)d_in[4];
  const float* bk = (const float*)d_in[5];
  const float* Wv = (const float*)d_in[6];
  const float* bv = (const float*)d_in[7];

  char* p = (char*)d_ws;
  auto grab = [&](size_t bytes) {
    char* r = p;
    p += (bytes + 255) & ~(size_t)255;
    return r;
  };
  _Float16* xh   = (_Float16*)grab((size_t)N * D * 2);
  _Float16* wqh  = (_Float16*)grab((size_t)D * D * 2);
  _Float16* wkh  = (_Float16*)grab((size_t)D * D * 2);
  _Float16* wvh  = (_Float16*)grab((size_t)D * D * 2);
  _Float16* Qh   = (_Float16*)grab((size_t)N * D * 2);   // pre-scaled by 1/32
  _Float16* Kh   = (_Float16*)grab((size_t)N * D * 2);
  _Float16* VTh  = (_Float16*)grab((size_t)D * N * 2);   // V^T [D x N]
  _Float16* Sh   = (_Float16*)grab((size_t)N * N * 2);   // S then P, in place
  float2*   part = (float2*)grab((size_t)N * 64 * sizeof(float2));
  float2*   fin  = (float2*)grab((size_t)N * sizeof(float2));

  cvt_k<<<N * D / 1024, 256, 0, stream>>>(x,  xh,  N * D);
  cvt_k<<<D * D / 1024, 256, 0, stream>>>(Wq, wqh, D * D);
  cvt_k<<<D * D / 1024, 256, 0, stream>>>(Wk, wkh, D * D);
  cvt_k<<<D * D / 1024, 256, 0, stream>>>(Wv, wvh, D * D);

  dim3 blk(256);
  // Q = (x Wq^T + bq) / sqrt(D);  K = x Wk^T + bk
  gemm_bt_k<1, 0><<<dim3(D / 128, N / 128), blk, 0, stream>>>(xh, wqh, Qh, bq, D, D, 1.0f / 32.0f);
  gemm_bt_k<1, 0><<<dim3(D / 128, N / 128), blk, 0, stream>>>(xh, wkh, Kh, bk, D, D, 1.0f);
  // V^T = Wv x^T + bv (bias per output row = per channel d)
  gemm_bt_k<2, 0><<<dim3(N / 128, D / 128), blk, 0, stream>>>(wvh, xh, VTh, bv, N, D, 1.0f);
  // S = Q K^T + decay bias, fp16 store + partial softmax stats
  gemm_stats_k<<<dim3(N / 128, N / 128), blk, 0, stream>>>(Qh, Kh, ts, Sh, part, N, D);
  combine_k<<<N / 256, 256, 0, stream>>>(part, fin);
  make_p_k<<<(int)(((long)N * N / 8) / 256), 256, 0, stream>>>(Sh, fin);
  // O = P V = P (V^T)^T -> BT-layout GEMM, fp32 output
  gemm_bt_k<0, 2><<<dim3(D / 128, N / 128), blk, 0, stream>>>(Sh, VTh, d_out, nullptr, D, N, 1.0f);
}

// Round 4
// 654.102 us; speedup vs baseline: 1.1378x; 1.1378x over previous
//
#include <hip/hip_runtime.h>

// TemporalAttention N=8192 D=1024, fp32 in/out, fp16-MFMA internals.
// v4: no-max softmax. gemm_stats stores U = exp(s-4) (fp16) + per-tile row
// sums; combine -> invL; PV GEMM computes O = (U V) * invL (row scale).
// make_p pass eliminated.

using half8   = __attribute__((ext_vector_type(8))) _Float16;
using half4   = __attribute__((ext_vector_type(4))) _Float16;
using floatx4 = __attribute__((ext_vector_type(4))) float;

__device__ __forceinline__ void gload_lds16(const void* g, void* l) {
  __builtin_amdgcn_global_load_lds((const __attribute__((address_space(1))) void*)g,
                                   (__attribute__((address_space(3))) void*)l,
                                   16, 0, 0);
}

// C = A(MxK) * B(NxK)^T, A/B row-major fp16, fp32 accum. 128x128 tile, BK=32,
// 4 waves of 4x4 16x16x32 MFMA.
// BIAS_MODE: 0 none, 1 add per-col, 2 add per-row, 3 MUL per-row (invL).
// OUT_MODE: 0 fp16, 2 fp32.
template<int BIAS_MODE, int OUT_MODE>
__global__ __launch_bounds__(256)
void gemm_bt_k(const _Float16* __restrict__ A, const _Float16* __restrict__ B,
               void* __restrict__ Cout, const float* __restrict__ bias,
               int Nld, int K, float outScale)
{
  __shared__ __align__(16) _Float16 As[128 * 32];
  __shared__ __align__(16) _Float16 Bs[128 * 32];
  const int tid = threadIdx.x;
  const int w = tid >> 6, lane = tid & 63;
  const int q = lane >> 4, l15 = lane & 15;
  const int wr = w >> 1, wc = w & 1;
  const long rowBase = (long)blockIdx.y * 128;
  const long colBase = (long)blockIdx.x * 128;

  // staging: tile elem e = w*1024 + s*512 + lane*8 -> row e/32, col e%32
  const int e0 = w * 1024 + lane * 8;
  const int r0 = e0 >> 5, c0 = e0 & 31;
  const int r1 = (e0 + 512) >> 5, c1 = (e0 + 512) & 31;
  const _Float16* Ag0 = A + (rowBase + r0) * K + c0;
  const _Float16* Ag1 = A + (rowBase + r1) * K + c1;
  const _Float16* Bg0 = B + (colBase + r0) * K + c0;
  const _Float16* Bg1 = B + (colBase + r1) * K + c1;
  _Float16* Al0 = &As[w * 1024];
  _Float16* Al1 = &As[w * 1024 + 512];
  _Float16* Bl0 = &Bs[w * 1024];
  _Float16* Bl1 = &Bs[w * 1024 + 512];

  floatx4 acc[4][4] = {};

  for (int k0 = 0; k0 < K; k0 += 32) {
    __syncthreads();
    gload_lds16(Ag0, Al0);
    gload_lds16(Ag1, Al1);
    gload_lds16(Bg0, Bl0);
    gload_lds16(Bg1, Bl1);
    Ag0 += 32; Ag1 += 32; Bg0 += 32; Bg1 += 32;
    __syncthreads();
    half8 a[4], b[4];
#pragma unroll
    for (int i = 0; i < 4; ++i)
      a[i] = *(const half8*)&As[(wr * 64 + 16 * i + l15) * 32 + q * 8];
#pragma unroll
    for (int j = 0; j < 4; ++j)
      b[j] = *(const half8*)&Bs[(wc * 64 + 16 * j + l15) * 32 + q * 8];
#pragma unroll
    for (int i = 0; i < 4; ++i)
#pragma unroll
      for (int j = 0; j < 4; ++j)
        acc[i][j] = __builtin_amdgcn_mfma_f32_16x16x32_f16(a[i], b[j], acc[i][j], 0, 0, 0);
  }

#pragma unroll
  for (int i = 0; i < 4; ++i) {
#pragma unroll
    for (int r = 0; r < 4; ++r) {
      const long rowg = rowBase + wr * 64 + 16 * i + q * 4 + r;
#pragma unroll
      for (int j = 0; j < 4; ++j) {
        const long colg = colBase + wc * 64 + 16 * j + l15;
        float v = acc[i][j][r];
        if (BIAS_MODE == 1) v += bias[colg];
        if (BIAS_MODE == 2) v += bias[rowg];
        if (BIAS_MODE == 3) v *= bias[rowg];
        v *= outScale;
        if (OUT_MODE == 2) ((float*)Cout)[rowg * Nld + colg] = v;
        else               ((_Float16*)Cout)[rowg * Nld + colg] = (_Float16)v;
      }
    }
  }
}

// U = exp(Q*K^T + decay_bias - 4), fp16; per-(row, col-tile) partial sum of U.
__global__ __launch_bounds__(256)
void gemm_stats_k(const _Float16* __restrict__ A, const _Float16* __restrict__ B,
                  const float* __restrict__ ts, _Float16* __restrict__ U,
                  float* __restrict__ part, int N, int K)
{
  __shared__ __align__(16) _Float16 As[128 * 32];
  __shared__ __align__(16) _Float16 Bs[128 * 32];
  __shared__ float trs[128], tcs[128];
  __shared__ float sL[2][2][64];
  const int tid = threadIdx.x;
  const int w = tid >> 6, lane = tid & 63;
  const int q = lane >> 4, l15 = lane & 15;
  const int wr = w >> 1, wc = w & 1;
  const long rowBase = (long)blockIdx.y * 128;
  const long colBase = (long)blockIdx.x * 128;

  if (tid < 128) {
    trs[tid] = ts[rowBase + tid];
    tcs[tid] = ts[colBase + tid];
  }

  const int e0 = w * 1024 + lane * 8;
  const int r0 = e0 >> 5, c0 = e0 & 31;
  const int r1 = (e0 + 512) >> 5, c1 = (e0 + 512) & 31;
  const _Float16* Ag0 = A + (rowBase + r0) * K + c0;
  const _Float16* Ag1 = A + (rowBase + r1) * K + c1;
  const _Float16* Bg0 = B + (colBase + r0) * K + c0;
  const _Float16* Bg1 = B + (colBase + r1) * K + c1;
  _Float16* Al0 = &As[w * 1024];
  _Float16* Al1 = &As[w * 1024 + 512];
  _Float16* Bl0 = &Bs[w * 1024];
  _Float16* Bl1 = &Bs[w * 1024 + 512];

  floatx4 acc[4][4] = {};

  for (int k0 = 0; k0 < K; k0 += 32) {
    __syncthreads();
    gload_lds16(Ag0, Al0);
    gload_lds16(Ag1, Al1);
    gload_lds16(Bg0, Bl0);
    gload_lds16(Bg1, Bl1);
    Ag0 += 32; Ag1 += 32; Bg0 += 32; Bg1 += 32;
    __syncthreads();
    half8 a[4], b[4];
#pragma unroll
    for (int i = 0; i < 4; ++i)
      a[i] = *(const half8*)&As[(wr * 64 + 16 * i + l15) * 32 + q * 8];
#pragma unroll
    for (int j = 0; j < 4; ++j)
      b[j] = *(const half8*)&Bs[(wc * 64 + 16 * j + l15) * 32 + q * 8];
#pragma unroll
    for (int i = 0; i < 4; ++i)
#pragma unroll
      for (int j = 0; j < 4; ++j)
        acc[i][j] = __builtin_amdgcn_mfma_f32_16x16x32_f16(a[i], b[j], acc[i][j], 0, 0, 0);
  }

  const float inv_td = 1.0f / 86400.0f;
  // u = exp(s - 4); s = qk + log-decay ~ qk - |dt|/TD (exact to 2.2e-6).
  // s in ~[-20, 7] so u fits fp16 with big margin; shift-invariant softmax.
#pragma unroll
  for (int i = 0; i < 4; ++i) {
#pragma unroll
    for (int r = 0; r < 4; ++r) {
      const int rowl = wr * 64 + 16 * i + q * 4 + r;
      float ls = 0.0f;
#pragma unroll
      for (int j = 0; j < 4; ++j) {
        const int coll = wc * 64 + 16 * j + l15;
        const float sv = acc[i][j][r] - fabsf(trs[rowl] - tcs[coll]) * inv_td - 4.0f;
        const float u = __expf(sv);
        ls += u;
        U[(rowBase + rowl) * (long)N + (colBase + coll)] = (_Float16)u;
      }
      // sum over the 16 lanes of the quad (64 cols of this wave-half)
      for (int mask = 1; mask <= 8; mask <<= 1)
        ls += __shfl_xor(ls, mask, 64);
      if (l15 == 0) sL[wr][wc][16 * i + 4 * q + r] = ls;
    }
  }
  __syncthreads();
  if (tid < 128) {
    const int wr2 = tid >> 6, rl = tid & 63;
    part[(rowBase + tid) * 64 + blockIdx.x] = sL[wr2][0][rl] + sL[wr2][1][rl];
  }
}

__global__ void combine_k(const float* __restrict__ part, float* __restrict__ invL) {
  const int r = blockIdx.x * 256 + threadIdx.x;
  float L = 0.0f;
  for (int c = 0; c < 64; ++c) L += part[(long)r * 64 + c];
  invL[r] = 1.0f / L;
}

// fp32 -> fp16, 4/thread
__global__ void cvt_k(const float* __restrict__ in, _Float16* __restrict__ out, int n) {
  const int i = (blockIdx.x * 256 + threadIdx.x) * 4;
  if (i >= n) return;
  const float4 v = *(const float4*)(in + i);
  half4 o = { (_Float16)v.x, (_Float16)v.y, (_Float16)v.z, (_Float16)v.w };
  *(half4*)(out + i) = o;
}

extern "C" void kernel_launch(void* const* d_in, const int* in_sizes, int n_in,
                              void* d_out, int out_size, void* d_ws, size_t ws_size,
                              hipStream_t stream)
{
  (void)in_sizes; (void)n_in; (void)out_size; (void)ws_size;
  const int N = 8192, D = 1024;
  const float* x  = (const float*)d_in[0];
  const float* ts = (const float*)d_in[1];
  const float* Wq = (const float*)d_in[2];
  const float* bq = (const float*)d_in[3];
  const float* Wk = (const float*)d_in[4];
  const float* bk = (const float*)d_in[5];
  const float* Wv = (const float*)d_in[6];
  const float* bv = (const float*)d_in[7];

  char* p = (char*)d_ws;
  auto grab = [&](size_t bytes) {
    char* r = p;
    p += (bytes + 255) & ~(size_t)255;
    return r;
  };
  _Float16* xh   = (_Float16*)grab((size_t)N * D * 2);
  _Float16* wqh  = (_Float16*)grab((size_t)D * D * 2);
  _Float16* wkh  = (_Float16*)grab((size_t)D * D * 2);
  _Float16* wvh  = (_Float16*)grab((size_t)D * D * 2);
  _Float16* Qh   = (_Float16*)grab((size_t)N * D * 2);   // pre-scaled by 1/32
  _Float16* Kh   = (_Float16*)grab((size_t)N * D * 2);
  _Float16* VTh  = (_Float16*)grab((size_t)D * N * 2);   // V^T [D x N]
  _Float16* Uh   = (_Float16*)grab((size_t)N * N * 2);   // U = exp(S - 4)
  float*    part = (float*)grab((size_t)N * 64 * sizeof(float));
  float*    invL = (float*)grab((size_t)N * sizeof(float));

  cvt_k<<<N * D / 1024, 256, 0, stream>>>(x,  xh,  N * D);
  cvt_k<<<D * D / 1024, 256, 0, stream>>>(Wq, wqh, D * D);
  cvt_k<<<D * D / 1024, 256, 0, stream>>>(Wk, wkh, D * D);
  cvt_k<<<D * D / 1024, 256, 0, stream>>>(Wv, wvh, D * D);

  dim3 blk(256);
  // Q = (x Wq^T + bq) / sqrt(D);  K = x Wk^T + bk
  gemm_bt_k<1, 0><<<dim3(D / 128, N / 128), blk, 0, stream>>>(xh, wqh, Qh, bq, D, D, 1.0f / 32.0f);
  gemm_bt_k<1, 0><<<dim3(D / 128, N / 128), blk, 0, stream>>>(xh, wkh, Kh, bk, D, D, 1.0f);
  // V^T = Wv x^T + bv (bias per output row = per channel d)
  gemm_bt_k<2, 0><<<dim3(N / 128, D / 128), blk, 0, stream>>>(wvh, xh, VTh, bv, N, D, 1.0f);
  // U = exp(Q K^T + decay - 4) + partial row sums
  gemm_stats_k<<<dim3(N / 128, N / 128), blk, 0, stream>>>(Qh, Kh, ts, Uh, part, N, D);
  combine_k<<<N / 256, 256, 0, stream>>>(part, invL);
  // O = (U V) * invL  -> BT-layout GEMM, fp32 output, per-row scale
  gemm_bt_k<3, 2><<<dim3(D / 128, N / 128), blk, 0, stream>>>(Uh, VTh, d_out, invL, D, N, 1.0f);
}

// Round 5
// 594.232 us; speedup vs baseline: 1.2524x; 1.1008x over previous
//
#include <hip/hip_runtime.h>

// TemporalAttention N=8192 D=1024, fp32 in/out, fp16-MFMA internals.
// v5: (a) XCD-aware tile swizzle on the PV GEMM — groups the 8 column-tiles
// sharing a U row-slice onto one XCD (b%8) so its private L2 serves 7/8 of
// the U traffic (FETCH was 820 MB vs 144 MB ideal). (b) Q and K projections
// merged into one GEMM into QKcat (ld=2048); 1/sqrt(D) folded into stats.

using half8   = __attribute__((ext_vector_type(8))) _Float16;
using half4   = __attribute__((ext_vector_type(4))) _Float16;
using floatx4 = __attribute__((ext_vector_type(4))) float;

__device__ __forceinline__ void gload_lds16(const void* g, void* l) {
  __builtin_amdgcn_global_load_lds((const __attribute__((address_space(1))) void*)g,
                                   (__attribute__((address_space(3))) void*)l,
                                   16, 0, 0);
}

// C[128y.., 128x..] = A(rows, lda) * B(rows, ldb)^T; fp16 in, fp32 accum.
// 128x128 tile, BK=32, 4 waves of 4x4 16x16x32 MFMA.
// BIAS_MODE: 0 none, 1 add per-col, 2 add per-row, 3 MUL per-row (invL).
// OUT_MODE: 0 fp16, 2 fp32.  SWZ: remap tiles so tileY = bflat % gridDim.y
// (same-Y tiles share an XCD under round-robin dispatch).
template<int BIAS_MODE, int OUT_MODE, int SWZ>
__global__ __launch_bounds__(256)
void gemm_bt_k(const _Float16* __restrict__ A, const _Float16* __restrict__ B,
               void* __restrict__ Cout, const float* __restrict__ bias,
               int lda, int ldb, int ldc, int K, float outScale)
{
  __shared__ __align__(16) _Float16 As[128 * 32];
  __shared__ __align__(16) _Float16 Bs[128 * 32];
  const int tid = threadIdx.x;
  const int w = tid >> 6, lane = tid & 63;
  const int q = lane >> 4, l15 = lane & 15;
  const int wr = w >> 1, wc = w & 1;

  int tx, ty;
  if (SWZ) {
    const int bflat = blockIdx.y * gridDim.x + blockIdx.x;  // dispatch-linear
    ty = bflat % gridDim.y;          // same ty -> same bflat%8 -> same XCD
    tx = bflat / gridDim.y;
  } else {
    tx = blockIdx.x; ty = blockIdx.y;
  }
  const long rowBase = (long)ty * 128;
  const long colBase = (long)tx * 128;

  // staging: tile elem e = w*1024 + s*512 + lane*8 -> row e/32, col e%32
  const int e0 = w * 1024 + lane * 8;
  const int r0 = e0 >> 5, c0 = e0 & 31;
  const int r1 = (e0 + 512) >> 5, c1 = (e0 + 512) & 31;
  const _Float16* Ag0 = A + (rowBase + r0) * lda + c0;
  const _Float16* Ag1 = A + (rowBase + r1) * lda + c1;
  const _Float16* Bg0 = B + (colBase + r0) * ldb + c0;
  const _Float16* Bg1 = B + (colBase + r1) * ldb + c1;
  _Float16* Al0 = &As[w * 1024];
  _Float16* Al1 = &As[w * 1024 + 512];
  _Float16* Bl0 = &Bs[w * 1024];
  _Float16* Bl1 = &Bs[w * 1024 + 512];

  floatx4 acc[4][4] = {};

  for (int k0 = 0; k0 < K; k0 += 32) {
    __syncthreads();
    gload_lds16(Ag0, Al0);
    gload_lds16(Ag1, Al1);
    gload_lds16(Bg0, Bl0);
    gload_lds16(Bg1, Bl1);
    Ag0 += 32; Ag1 += 32; Bg0 += 32; Bg1 += 32;
    __syncthreads();
    half8 a[4], b[4];
#pragma unroll
    for (int i = 0; i < 4; ++i)
      a[i] = *(const half8*)&As[(wr * 64 + 16 * i + l15) * 32 + q * 8];
#pragma unroll
    for (int j = 0; j < 4; ++j)
      b[j] = *(const half8*)&Bs[(wc * 64 + 16 * j + l15) * 32 + q * 8];
#pragma unroll
    for (int i = 0; i < 4; ++i)
#pragma unroll
      for (int j = 0; j < 4; ++j)
        acc[i][j] = __builtin_amdgcn_mfma_f32_16x16x32_f16(a[i], b[j], acc[i][j], 0, 0, 0);
  }

#pragma unroll
  for (int i = 0; i < 4; ++i) {
#pragma unroll
    for (int r = 0; r < 4; ++r) {
      const long rowg = rowBase + wr * 64 + 16 * i + q * 4 + r;
#pragma unroll
      for (int j = 0; j < 4; ++j) {
        const long colg = colBase + wc * 64 + 16 * j + l15;
        float v = acc[i][j][r];
        if (BIAS_MODE == 1) v += bias[colg];
        if (BIAS_MODE == 2) v += bias[rowg];
        if (BIAS_MODE == 3) v *= bias[rowg];
        v *= outScale;
        if (OUT_MODE == 2) ((float*)Cout)[rowg * ldc + colg] = v;
        else               ((_Float16*)Cout)[rowg * ldc + colg] = (_Float16)v;
      }
    }
  }
}

// U = exp(qkScale*(Q*K^T) + decay_bias - 4), fp16; per-(row,col-tile) row sums.
__global__ __launch_bounds__(256)
void gemm_stats_k(const _Float16* __restrict__ A, const _Float16* __restrict__ B,
                  const float* __restrict__ ts, _Float16* __restrict__ U,
                  float* __restrict__ part, int lda, int ldb, int N, int K,
                  float qkScale)
{
  __shared__ __align__(16) _Float16 As[128 * 32];
  __shared__ __align__(16) _Float16 Bs[128 * 32];
  __shared__ float trs[128], tcs[128];
  __shared__ float sL[2][2][64];
  const int tid = threadIdx.x;
  const int w = tid >> 6, lane = tid & 63;
  const int q = lane >> 4, l15 = lane & 15;
  const int wr = w >> 1, wc = w & 1;
  const long rowBase = (long)blockIdx.y * 128;
  const long colBase = (long)blockIdx.x * 128;

  if (tid < 128) {
    trs[tid] = ts[rowBase + tid];
    tcs[tid] = ts[colBase + tid];
  }

  const int e0 = w * 1024 + lane * 8;
  const int r0 = e0 >> 5, c0 = e0 & 31;
  const int r1 = (e0 + 512) >> 5, c1 = (e0 + 512) & 31;
  const _Float16* Ag0 = A + (rowBase + r0) * lda + c0;
  const _Float16* Ag1 = A + (rowBase + r1) * lda + c1;
  const _Float16* Bg0 = B + (colBase + r0) * ldb + c0;
  const _Float16* Bg1 = B + (colBase + r1) * ldb + c1;
  _Float16* Al0 = &As[w * 1024];
  _Float16* Al1 = &As[w * 1024 + 512];
  _Float16* Bl0 = &Bs[w * 1024];
  _Float16* Bl1 = &Bs[w * 1024 + 512];

  floatx4 acc[4][4] = {};

  for (int k0 = 0; k0 < K; k0 += 32) {
    __syncthreads();
    gload_lds16(Ag0, Al0);
    gload_lds16(Ag1, Al1);
    gload_lds16(Bg0, Bl0);
    gload_lds16(Bg1, Bl1);
    Ag0 += 32; Ag1 += 32; Bg0 += 32; Bg1 += 32;
    __syncthreads();
    half8 a[4], b[4];
#pragma unroll
    for (int i = 0; i < 4; ++i)
      a[i] = *(const half8*)&As[(wr * 64 + 16 * i + l15) * 32 + q * 8];
#pragma unroll
    for (int j = 0; j < 4; ++j)
      b[j] = *(const half8*)&Bs[(wc * 64 + 16 * j + l15) * 32 + q * 8];
#pragma unroll
    for (int i = 0; i < 4; ++i)
#pragma unroll
      for (int j = 0; j < 4; ++j)
        acc[i][j] = __builtin_amdgcn_mfma_f32_16x16x32_f16(a[i], b[j], acc[i][j], 0, 0, 0);
  }

  const float inv_td = 1.0f / 86400.0f;
  // u = exp(s - 4); s = qk/32 + log-decay ~ qk/32 - |dt|/TD (exact to 2.2e-6).
  // s in ~[-20, 7] so u fits fp16 with big margin; shift-invariant softmax.
#pragma unroll
  for (int i = 0; i < 4; ++i) {
#pragma unroll
    for (int r = 0; r < 4; ++r) {
      const int rowl = wr * 64 + 16 * i + q * 4 + r;
      float ls = 0.0f;
#pragma unroll
      for (int j = 0; j < 4; ++j) {
        const int coll = wc * 64 + 16 * j + l15;
        const float sv = acc[i][j][r] * qkScale
                       - fabsf(trs[rowl] - tcs[coll]) * inv_td - 4.0f;
        const float u = __expf(sv);
        ls += u;
        U[(rowBase + rowl) * (long)N + (colBase + coll)] = (_Float16)u;
      }
      for (int mask = 1; mask <= 8; mask <<= 1)
        ls += __shfl_xor(ls, mask, 64);
      if (l15 == 0) sL[wr][wc][16 * i + 4 * q + r] = ls;
    }
  }
  __syncthreads();
  if (tid < 128) {
    const int wr2 = tid >> 6, rl = tid & 63;
    part[(rowBase + tid) * 64 + blockIdx.x] = sL[wr2][0][rl] + sL[wr2][1][rl];
  }
}

__global__ void combine_k(const float* __restrict__ part, float* __restrict__ invL) {
  const int r = blockIdx.x * 256 + threadIdx.x;
  float L = 0.0f;
  for (int c = 0; c < 64; ++c) L += part[(long)r * 64 + c];
  invL[r] = 1.0f / L;
}

// fp32 -> fp16, 4/thread
__global__ void cvt_k(const float* __restrict__ in, _Float16* __restrict__ out, int n) {
  const int i = (blockIdx.x * 256 + threadIdx.x) * 4;
  if (i >= n) return;
  const float4 v = *(const float4*)(in + i);
  half4 o = { (_Float16)v.x, (_Float16)v.y, (_Float16)v.z, (_Float16)v.w };
  *(half4*)(out + i) = o;
}

extern "C" void kernel_launch(void* const* d_in, const int* in_sizes, int n_in,
                              void* d_out, int out_size, void* d_ws, size_t ws_size,
                              hipStream_t stream)
{
  (void)in_sizes; (void)n_in; (void)out_size; (void)ws_size;
  const int N = 8192, D = 1024;
  const float* x  = (const float*)d_in[0];
  const float* ts = (const float*)d_in[1];
  const float* Wq = (const float*)d_in[2];
  const float* bq = (const float*)d_in[3];
  const float* Wk = (const float*)d_in[4];
  const float* bk = (const float*)d_in[5];
  const float* Wv = (const float*)d_in[6];
  const float* bv = (const float*)d_in[7];

  char* p = (char*)d_ws;
  auto grab = [&](size_t bytes) {
    char* r = p;
    p += (bytes + 255) & ~(size_t)255;
    return r;
  };
  _Float16* xh    = (_Float16*)grab((size_t)N * D * 2);
  _Float16* wqkh  = (_Float16*)grab((size_t)2 * D * D * 2); // Wq rows then Wk rows
  _Float16* wvh   = (_Float16*)grab((size_t)D * D * 2);
  _Float16* QKcat = (_Float16*)grab((size_t)N * 2 * D * 2); // [N x 2D], Q | K
  _Float16* VTh   = (_Float16*)grab((size_t)D * N * 2);     // V^T [D x N]
  _Float16* Uh    = (_Float16*)grab((size_t)N * N * 2);     // U = exp(S - 4)
  float*    part  = (float*)grab((size_t)N * 64 * sizeof(float));
  float*    invL  = (float*)grab((size_t)N * sizeof(float));
  float*    bcat  = (float*)grab((size_t)2 * D * sizeof(float));

  cvt_k<<<N * D / 1024, 256, 0, stream>>>(x,  xh,  N * D);
  cvt_k<<<D * D / 1024, 256, 0, stream>>>(Wq, wqkh,         D * D);
  cvt_k<<<D * D / 1024, 256, 0, stream>>>(Wk, wqkh + D * D, D * D);
  cvt_k<<<D * D / 1024, 256, 0, stream>>>(Wv, wvh, D * D);
  hipMemcpyAsync(bcat,     bq, D * sizeof(float), hipMemcpyDeviceToDevice, stream);
  hipMemcpyAsync(bcat + D, bk, D * sizeof(float), hipMemcpyDeviceToDevice, stream);

  dim3 blk(256);
  // [Q | K] = x [Wq;Wk]^T + [bq|bk]   (unscaled; 1/32 folded into stats)
  gemm_bt_k<1, 0, 0><<<dim3(2 * D / 128, N / 128), blk, 0, stream>>>(
      xh, wqkh, QKcat, bcat, D, D, 2 * D, D, 1.0f);
  // V^T = Wv x^T + bv (bias per output row = per channel d)
  gemm_bt_k<2, 0, 0><<<dim3(N / 128, D / 128), blk, 0, stream>>>(
      wvh, xh, VTh, bv, D, D, N, D, 1.0f);
  // U = exp(QK^T/32 + decay - 4) + partial row sums
  gemm_stats_k<<<dim3(N / 128, N / 128), blk, 0, stream>>>(
      QKcat, QKcat + D, ts, Uh, part, 2 * D, 2 * D, N, D, 1.0f / 32.0f);
  combine_k<<<N / 256, 256, 0, stream>>>(part, invL);
  // O = (U V) * invL — XCD-swizzled so same-row tiles share an XCD's L2
  gemm_bt_k<3, 2, 1><<<dim3(D / 128, N / 128), blk, 0, stream>>>(
      Uh, VTh, d_out, invL, N, N, D, N, 1.0f);
}